// Round 5
// baseline (22730.673 us; speedup 1.0000x reference)
//
#include <hip/hip_runtime.h>
#include <math.h>

// ToxicityLSTM: 2-layer LSTM (B=64, T=1024, H=256, gates i,j,f,o, forget
// bias 1.0) + linear head (256->6) + sigmoid + threshold.
//
// Round 5: back to R3's proven lockstep skeleton (R4's distributed flags
// saturated the coherent fabric with redundant polls) + three fixes:
//   - DENSE flags (4B stride): a poll sweep = 8 lines, not 64 -> 16x less
//     coherent poll traffic than R3. One polling wave per block (wave 0).
//   - 2 blocks/CU: 512 blocks x 512 threads, block = 4 units x 16 batches,
//     54.3 KB LDS/block, VGPR<=128 (launch_bounds(512,4)). Co-resident
//     blocks from different batch-groups hide each other's barrier/staging
//     stalls (independent timelines).
//   - blockIdx interleave: bgrp = blk&3 so adjacent blocks differ in group.
//   - Lockstep epoch barrier per superstep (all inputs for superstep s are
//     produced in superstep s-1): flag[block] = s+1 after wave0's coherent
//     h-stores drain (vmcnt(0)); wave0 polls the group's 128 flags (dwordx2
//     per lane over dense 512B); two compute syncs + one barrier sync.

#define BB 64
#define TT 1024
#define HH 256
#define NTHREADS 512
#define NBLKS 512
#define FLAG_BYTES 4096                  // 4 bgrp x 128 ints (dense) + pad
#define HBUF_FLOATS (BB * HH)            // 16384 floats per slot
#define WT_FLOATS (256 * 4 * 512)        // 524288 floats per layer
#define WS_NEEDED (FLAG_BYTES + (size_t)4 * HBUF_FLOATS * 4 + (size_t)2 * WT_FLOATS * 4)
#define HROW 576                         // skewed panel row stride (floats)

typedef float f32x4 __attribute__((ext_vector_type(4)));
typedef int   i32x2 __attribute__((ext_vector_type(2)));

__device__ __forceinline__ void coh_store(float* p, float v) {
  __hip_atomic_store(p, v, __ATOMIC_RELAXED, __HIP_MEMORY_SCOPE_AGENT);
}
__device__ __forceinline__ void coh_store_i(int* p, int v) {
  __hip_atomic_store(p, v, __ATOMIC_RELAXED, __HIP_MEMORY_SCOPE_AGENT);
}

// 4 device-coherent float4 loads in flight, one vmcnt drain.
__device__ __forceinline__ void coh_load4(
    const float* p0, const float* p1, const float* p2, const float* p3,
    f32x4& a0, f32x4& a1, f32x4& a2, f32x4& a3) {
  asm volatile(
      "global_load_dwordx4 %0, %4, off sc0 sc1\n\t"
      "global_load_dwordx4 %1, %5, off sc0 sc1\n\t"
      "global_load_dwordx4 %2, %6, off sc0 sc1\n\t"
      "global_load_dwordx4 %3, %7, off sc0 sc1\n\t"
      "s_waitcnt vmcnt(0)"
      : "=&v"(a0), "=&v"(a1), "=&v"(a2), "=&v"(a3)
      : "v"(p0), "v"(p1), "v"(p2), "v"(p3)
      : "memory");
}

// One-time weight transpose: src [512 k][4 g * 256 u] -> dst [256 u][4 g][512 k]
__global__ void transpose_w(const float* __restrict__ src, float* __restrict__ dst) {
  __shared__ float t[64][65];
  const int g  = blockIdx.x;   // 4
  const int kt = blockIdx.y;   // 8 tiles over 512 k
  const int ut = blockIdx.z;   // 4 tiles over 256 u
  const int tx = threadIdx.x & 63;
  const int ty = threadIdx.x >> 6;
  #pragma unroll
  for (int r = ty; r < 64; r += 4)
    t[r][tx] = src[(size_t)(kt * 64 + r) * 1024 + g * 256 + ut * 64 + tx];
  __syncthreads();
  #pragma unroll
  for (int r = ty; r < 64; r += 4)
    dst[((size_t)(ut * 64 + r) * 4 + g) * 512 + kt * 64 + tx] = t[tx][r];
}

__global__ __launch_bounds__(NTHREADS, 4) void lstm2_persistent(
    const float* __restrict__ x,
    const float* __restrict__ b0, const float* __restrict__ b1,
    const float* __restrict__ wt0, const float* __restrict__ wt1,
    float* __restrict__ h1buf, float* __restrict__ h2buf,
    int* __restrict__ flags)
{
  __shared__ float hstage[16 * HROW];   // 36864 B operand panel (skewed)
  __shared__ f32x4 part[64 * 17];       // 17408 B k-partials (padded)

  const int blk   = blockIdx.x;
  const int bgrp  = blk & 3;                    // interleaved: co-resident
  const int taskB = (blk >> 2) & 1;             //   blocks differ in bgrp
  const int ublk  = blk >> 3;                   // 0..63 (4 units each)

  const int tid  = threadIdx.x;
  const int lane = tid & 63;
  const int ul   = tid & 3;
  const int kq   = (tid >> 2) & 15;
  const int bt   = tid >> 6;                    // wave id; 2 b-rows each
  const int cS   = tid & 127;                   // staging f4-col; even waves
  const int rS   = tid >> 7;                    //   c<64 (low), odd high
  const int dposS = cS * 4 + (cS >> 3) * 4;     // skewed in-row position

  const float* WT   = taskB ? wt1 : wt0;
  const float* bias = taskB ? b1 : b0;
  const float* wb   = WT + (size_t)(ublk * 4 + ul) * 2048 + kq * 32;

  // ---- finisher state (wave 0: threads 0..63 own one (b,u)) ----
  float bi = 0.f, bj = 0.f, bfv = 0.f, bo = 0.f;
  if (tid < 64) {
    const int u = ublk * 4 + (tid & 3);
    bi  = bias[u];
    bj  = bias[256 + u];
    bfv = bias[512 + u];
    bo  = bias[768 + u];
  }
  float cst = 0.f;

  int* myflag = flags + bgrp * 128 + taskB * 64 + ublk;

  for (int s = 0; s <= TT; ++s) {
    const bool active = taskB ? (s >= 1) : (s < TT);
    const float* h1prev = h1buf + (size_t)((s + 1) & 1) * HBUF_FLOATS; // h1(s-1)

    if (active) {
      const int t = taskB ? (s - 1) : s;

      // ---- stage operand panel [16 b][512 k]; 4 rows per thread ----
      f32x4 v0, v1, v2, v3;
      if (!taskB && cS < 64) {
        // L1 low half = x(t): plain cacheable loads (wave-uniform branch)
        const float* bx = x + ((size_t)(bgrp * 16 + rS) * TT + t) * HH + lane * 4;
        const size_t rstep = (size_t)4 * TT * HH;
        v0 = *(const f32x4*)(bx);
        v1 = *(const f32x4*)(bx + rstep);
        v2 = *(const f32x4*)(bx + 2 * rstep);
        v3 = *(const f32x4*)(bx + 3 * rstep);
      } else {
        const float* src;
        if (!taskB)       src = h1prev;                                 // L1 high = h1(s-1)
        else if (cS < 64) src = h1prev;                                 // L2 low  = h1(s-1)
        else              src = h2buf + (size_t)(s & 1) * HBUF_FLOATS;  // L2 high = h2(s-2)
        const float* p0 = src + (size_t)(bgrp * 16 + rS) * HH + lane * 4;
        coh_load4(p0, p0 + 4 * HH, p0 + 8 * HH, p0 + 12 * HH, v0, v1, v2, v3);
      }
      *(f32x4*)&hstage[(rS + 0)  * HROW + dposS] = v0;
      *(f32x4*)&hstage[(rS + 4)  * HROW + dposS] = v1;
      *(f32x4*)&hstage[(rS + 8)  * HROW + dposS] = v2;
      *(f32x4*)&hstage[(rS + 12) * HROW + dposS] = v3;
      __syncthreads();

      // ---- gemv: 2 b-rows x 4 gates over 32-k slice; W streamed from L1/L2 ----
      float acc[2][4];
      #pragma unroll
      for (int j = 0; j < 2; ++j)
        #pragma unroll
        for (int g = 0; g < 4; ++g) acc[j][g] = 0.f;

      const float* hp0 = &hstage[(bt * 2 + 0) * HROW + kq * 36];
      const float* hp1 = &hstage[(bt * 2 + 1) * HROW + kq * 36];
      #pragma unroll 4
      for (int cc = 0; cc < 8; ++cc) {
        f32x4 w0 = *(const f32x4*)(wb + 0 * 512 + cc * 4);
        f32x4 w1 = *(const f32x4*)(wb + 1 * 512 + cc * 4);
        f32x4 w2 = *(const f32x4*)(wb + 2 * 512 + cc * 4);
        f32x4 w3 = *(const f32x4*)(wb + 3 * 512 + cc * 4);
        const f32x4 ha = *(const f32x4*)(hp0 + cc * 4);
        const f32x4 hc = *(const f32x4*)(hp1 + cc * 4);
        #pragma unroll
        for (int e = 0; e < 4; ++e) {
          acc[0][0] = fmaf(ha[e], w0[e], acc[0][0]);
          acc[0][1] = fmaf(ha[e], w1[e], acc[0][1]);
          acc[0][2] = fmaf(ha[e], w2[e], acc[0][2]);
          acc[0][3] = fmaf(ha[e], w3[e], acc[0][3]);
          acc[1][0] = fmaf(hc[e], w0[e], acc[1][0]);
          acc[1][1] = fmaf(hc[e], w1[e], acc[1][1]);
          acc[1][2] = fmaf(hc[e], w2[e], acc[1][2]);
          acc[1][3] = fmaf(hc[e], w3[e], acc[1][3]);
        }
      }

      // ---- 16-way k-combine via padded LDS partials ----
      #pragma unroll
      for (int j = 0; j < 2; ++j) {
        f32x4 p = { acc[j][0], acc[j][1], acc[j][2], acc[j][3] };
        part[((bt * 2 + j) * 4 + ul) * 17 + kq] = p;
      }
      __syncthreads();

      // ---- finish: wave 0 owns (b = tid>>2, u = ublk*4 + (tid&3)) ----
      if (tid < 64) {
        float gi = bi, gj = bj, gf = bfv, go = bo;
        #pragma unroll
        for (int q = 0; q < 16; ++q) {
          const f32x4 p = part[tid * 17 + q];
          gi += p[0]; gj += p[1]; gf += p[2]; go += p[3];
        }
        const float ig = 1.f / (1.f + expf(-gi));
        const float jt = tanhf(gj);
        const float fg = 1.f / (1.f + expf(-(gf + 1.0f)));
        const float og = 1.f / (1.f + expf(-go));
        cst = fg * cst + ig * jt;
        const float hn = og * tanhf(cst);

        float* hb = taskB ? (h2buf + (size_t)((s + 1) & 1) * HBUF_FLOATS)  // h2(s-1)
                          : (h1buf + (size_t)(s & 1) * HBUF_FLOATS);       // h1(s)
        coh_store(hb + (size_t)(bgrp * 16 + (tid >> 2)) * HH + ublk * 4 + (tid & 3), hn);
        asm volatile("s_waitcnt vmcnt(0)" ::: "memory");   // h visible before flag
      }
    }

    // ---- lockstep epoch barrier over the bgrp's 128 blocks (dense flags) ----
    if (s < TT) {
      if (tid == 0) coh_store_i(myflag, s + 1);
      if (tid < 64) {
        const int* fp = flags + bgrp * 128 + tid * 2;
        for (;;) {
          i32x2 f;
          asm volatile(
              "global_load_dwordx2 %0, %1, off sc0 sc1\n\t"
              "s_waitcnt vmcnt(0)"
              : "=v"(f) : "v"(fp) : "memory");
          const int v = f[0] < f[1] ? f[0] : f[1];
          if (__all(v >= s + 1)) break;
          __builtin_amdgcn_s_sleep(1);
        }
      }
      __syncthreads();
    }
  }
}

// Head: logits = h2_last @ w_out + b_out; sigmoid; threshold.
__global__ void head_kernel(const float* __restrict__ h2last,
                            const float* __restrict__ w_out,
                            const float* __restrict__ b_out,
                            float* __restrict__ out)
{
  int tid = threadIdx.x;
  if (tid >= 384) return;
  int bb = tid / 6, cc = tid % 6;
  float acc = b_out[cc];
  const float* hr = h2last + bb * HH;
  #pragma unroll 4
  for (int uu = 0; uu < HH; ++uu) acc = fmaf(hr[uu], w_out[uu * 6 + cc], acc);
  out[tid] = acc;                            // logits
  float sg = 1.f / (1.f + expf(-acc));
  out[384 + tid] = sg;                       // sigmoid output
  out[768 + tid] = (sg > 0.5f) ? 1.f : 0.f;  // prediction
}

extern "C" void kernel_launch(void* const* d_in, const int* in_sizes, int n_in,
                              void* d_out, int out_size, void* d_ws, size_t ws_size,
                              hipStream_t stream) {
  const float* x     = (const float*)d_in[0];
  const float* k0    = (const float*)d_in[1];
  const float* b0    = (const float*)d_in[2];
  const float* k1    = (const float*)d_in[3];
  const float* b1    = (const float*)d_in[4];
  const float* w_out = (const float*)d_in[5];
  const float* b_out = (const float*)d_in[6];
  float* out = (float*)d_out;

  if (ws_size < WS_NEEDED) return;  // visible failure if ws too small

  int*   flags = (int*)d_ws;
  float* h1b   = (float*)((char*)d_ws + FLAG_BYTES);
  float* h2b   = h1b + 2 * HBUF_FLOATS;
  float* wt0   = h2b + 2 * HBUF_FLOATS;
  float* wt1   = wt0 + WT_FLOATS;

  // Zero flags + h slots (h(-1)=c(-1)=0): graph-replay deterministic.
  hipMemsetAsync(d_ws, 0, FLAG_BYTES + (size_t)4 * HBUF_FLOATS * 4, stream);

  transpose_w<<<dim3(4, 8, 4), 256, 0, stream>>>(k0, wt0);
  transpose_w<<<dim3(4, 8, 4), 256, 0, stream>>>(k1, wt1);

  lstm2_persistent<<<NBLKS, NTHREADS, 0, stream>>>(x, b0, b1, wt0, wt1,
                                                   h1b, h2b, flags);

  // h2(1023) lives in slot 1023&1 = 1
  head_kernel<<<1, 384, 0, stream>>>(h2b + HBUF_FLOATS, w_out, b_out, out);
}

// Round 7
// 4135.653 us; speedup vs baseline: 5.4963x; 5.4963x over previous
//
#include <hip/hip_runtime.h>
#include <math.h>

// ToxicityLSTM: 2-layer LSTM (B=64, T=1024, H=256, gates i,j,f,o, forget
// bias 1.0) + linear head (256->6) + sigmoid + threshold.
//
// Round 7 = R3 skeleton (proven 3.97 ms) + dense flags + finisher-direct
// flag store + deep pipeline with SAFE LDS prefetch.
//   - 256 blocks x 512 threads, 1 block/CU. Blocks 0..127: layer1 @ t=s.
//     Blocks 128..255: layer2 @ t=s-2 (deep pipeline -> L2's h1 operand is
//     age-2, prefetchable one superstep early).
//   - W slice [4g][32k] in VGPRs per thread (loop-invariant). Skewed hstage
//     (0 bank conflicts, R3-verified). 16-way k-combine via padded partials;
//     finisher waves 0-1 own (b,u), c in registers.
//   - Low panel half (x(t) for L1 / h1(t) for L2) is prefetched into LDS at
//     the END of the previous superstep with a BLOCKING load (no in-flight
//     registers cross compiler-visible code -- the R6 bug). The load hides
//     in the barrier wait; post-barrier coherent staging halves to 16 KB
//     (high half only: h1(s-1) for L1, h2(s-3) for L2).
//   - Dense flags (8 B/block): two per block, stored by each finisher wave
//     directly after its own vmcnt(0) h-store drain. Wave 0 polls all 64
//     block-flag-pairs of its batch group (dwordx2/lane, 512 B sweep).
//
// Slot map (verified): h1 quad-buffered slot t&3; h2 double-buffered slot
// t&1. L1@s: low=x(s) [prefetched], high=h1(s-1) slot (s-1)&3, out h1(s)
// slot s&3. L2@s: low=h1(s-2) slot (s-2)&3 [prefetched at end of s-1],
// high=h2(s-3) slot (s+1)&1, out h2(s-2) slot s&1. Head reads h2(1023)
// slot 1. Max inter-block skew = 1 superstep (barrier), h1 slot distance 4.

#define BB 64
#define TT 1024
#define HH 256
#define NTHREADS 512
#define FLAG_BYTES 4096                  // 4 bgrp x 64 blk x 2 ints, dense
#define HBUF_FLOATS (BB * HH)            // 16384 floats per slot
#define WT_FLOATS (256 * 4 * 512)        // 524288 floats per layer
#define WS_NEEDED (FLAG_BYTES + (size_t)6 * HBUF_FLOATS * 4 + (size_t)2 * WT_FLOATS * 4)
#define HROW 576                         // skewed panel row stride (floats)

typedef float f32x4 __attribute__((ext_vector_type(4)));
typedef int   i32x2 __attribute__((ext_vector_type(2)));

__device__ __forceinline__ void coh_store(float* p, float v) {
  __hip_atomic_store(p, v, __ATOMIC_RELAXED, __HIP_MEMORY_SCOPE_AGENT);
}
__device__ __forceinline__ void coh_store_i(int* p, int v) {
  __hip_atomic_store(p, v, __ATOMIC_RELAXED, __HIP_MEMORY_SCOPE_AGENT);
}

// 4 device-coherent float4 loads in flight, one vmcnt drain (BLOCKING).
__device__ __forceinline__ void coh_load4(
    const float* p0, const float* p1, const float* p2, const float* p3,
    f32x4& a0, f32x4& a1, f32x4& a2, f32x4& a3) {
  asm volatile(
      "global_load_dwordx4 %0, %4, off sc0 sc1\n\t"
      "global_load_dwordx4 %1, %5, off sc0 sc1\n\t"
      "global_load_dwordx4 %2, %6, off sc0 sc1\n\t"
      "global_load_dwordx4 %3, %7, off sc0 sc1\n\t"
      "s_waitcnt vmcnt(0)"
      : "=&v"(a0), "=&v"(a1), "=&v"(a2), "=&v"(a3)
      : "v"(p0), "v"(p1), "v"(p2), "v"(p3)
      : "memory");
}

// One-time weight transpose: src [512 k][4 g * 256 u] -> dst [256 u][4 g][512 k]
__global__ void transpose_w(const float* __restrict__ src, float* __restrict__ dst) {
  __shared__ float t[64][65];
  const int g  = blockIdx.x;   // 4
  const int kt = blockIdx.y;   // 8 tiles over 512 k
  const int ut = blockIdx.z;   // 4 tiles over 256 u
  const int tx = threadIdx.x & 63;
  const int ty = threadIdx.x >> 6;
  #pragma unroll
  for (int r = ty; r < 64; r += 4)
    t[r][tx] = src[(size_t)(kt * 64 + r) * 1024 + g * 256 + ut * 64 + tx];
  __syncthreads();
  #pragma unroll
  for (int r = ty; r < 64; r += 4)
    dst[((size_t)(ut * 64 + r) * 4 + g) * 512 + kt * 64 + tx] = t[tx][r];
}

__global__ __launch_bounds__(NTHREADS, 2) void lstm2_persistent(
    const float* __restrict__ x,
    const float* __restrict__ b0, const float* __restrict__ b1,
    const float* __restrict__ wt0, const float* __restrict__ wt1,
    float* __restrict__ h1buf, float* __restrict__ h2buf,
    int* __restrict__ flags)
{
  __shared__ float hstage[16 * HROW];   // 36864 B operand panel (skewed)
  __shared__ f32x4 part[128 * 17];      // 34816 B k-partials (padded)

  const int blk   = blockIdx.x;
  const int taskB = blk >= 128;                  // layer2 blocks
  const int tblk  = taskB ? blk - 128 : blk;
  const int bgrp  = tblk >> 5;                   // 4 groups of 16 b
  const int ublk  = tblk & 31;                   // 32 groups of 8 u

  const int tid  = threadIdx.x;
  const int lane = tid & 63;
  const int ul   = tid & 7;
  const int kq   = (tid >> 3) & 15;
  const int bt   = tid >> 7;
  const int cS   = tid & 127;                    // staging f4-col 0..127
  const int rS   = tid >> 7;                     // staging base row 0..3
  const int dposS = cS * 4 + (cS >> 3) * 4;      // skewed in-row position
  const bool evenW = (cS < 64);                  // wave-uniform: low half

  const float* WT   = taskB ? wt1 : wt0;
  const float* bias = taskB ? b1 : b0;

  // ---- loop-invariant weight slice into registers: [4 g][32 k] ----
  f32x4 w[4][8];
  {
    const float* wb = WT + (size_t)(ublk * 8 + ul) * 2048 + kq * 32;
    #pragma unroll
    for (int g = 0; g < 4; ++g)
      #pragma unroll
      for (int cc = 0; cc < 8; ++cc)
        w[g][cc] = *(const f32x4*)(wb + g * 512 + cc * 4);
  }

  // ---- finisher state (threads 0..127 own one (b,u)) ----
  float bi = 0.f, bj = 0.f, bfv = 0.f, bo = 0.f;
  if (tid < 128) {
    const int u = ublk * 8 + (tid & 7);
    bi  = bias[u];
    bj  = bias[256 + u];
    bfv = bias[512 + u];
    bo  = bias[768 + u];
  }
  float cst = 0.f;

  int* myflag = flags + ((size_t)bgrp * 64 + (taskB ? 32 : 0) + ublk) * 2;
  const size_t rstep = (size_t)4 * TT * HH;

  // ---- prologue: L1 pre-stages x(0) into hstage low (blocking, plain) ----
  if (!taskB && evenW) {
    const float* bx = x + ((size_t)(bgrp * 16 + rS) * TT + 0) * HH + lane * 4;
    f32x4 v0 = *(const f32x4*)(bx);
    f32x4 v1 = *(const f32x4*)(bx + rstep);
    f32x4 v2 = *(const f32x4*)(bx + 2 * rstep);
    f32x4 v3 = *(const f32x4*)(bx + 3 * rstep);
    *(f32x4*)&hstage[(rS + 0)  * HROW + dposS] = v0;
    *(f32x4*)&hstage[(rS + 4)  * HROW + dposS] = v1;
    *(f32x4*)&hstage[(rS + 8)  * HROW + dposS] = v2;
    *(f32x4*)&hstage[(rS + 12) * HROW + dposS] = v3;
  }

  // L1 processes t=s (active s<TT); L2 processes t=s-2 (active 2<=s<=TT+1).
  for (int s = 0; s <= TT + 1; ++s) {
    const bool active = taskB ? (s >= 2) : (s < TT);

    if (active) {
      // ---- stage HIGH panel half only (odd waves), post-barrier ----
      if (!evenW) {
        const float* src = taskB
            ? (h2buf + (size_t)((s + 1) & 1) * HBUF_FLOATS)   // h2(s-3)
            : (h1buf + (size_t)((s - 1) & 3) * HBUF_FLOATS);  // h1(s-1)
        const float* p0 = src + (size_t)(bgrp * 16 + rS) * HH + lane * 4;
        f32x4 v0, v1, v2, v3;
        coh_load4(p0, p0 + 4 * HH, p0 + 8 * HH, p0 + 12 * HH, v0, v1, v2, v3);
        *(f32x4*)&hstage[(rS + 0)  * HROW + dposS] = v0;
        *(f32x4*)&hstage[(rS + 4)  * HROW + dposS] = v1;
        *(f32x4*)&hstage[(rS + 8)  * HROW + dposS] = v2;
        *(f32x4*)&hstage[(rS + 12) * HROW + dposS] = v3;
      }
      __syncthreads();   // (A) panel complete (low was pre-staged)

      // ---- gemv: 4 b x 4 g accumulators over 32-k slice (R3 verbatim) ----
      float acc[4][4];
      #pragma unroll
      for (int b4 = 0; b4 < 4; ++b4)
        #pragma unroll
        for (int g = 0; g < 4; ++g) acc[b4][g] = 0.f;

      const int kbase = kq * 36;
      #pragma unroll
      for (int b4 = 0; b4 < 4; ++b4) {
        const float* hp = &hstage[(bt * 4 + b4) * HROW + kbase];
        #pragma unroll
        for (int cc = 0; cc < 8; ++cc) {
          const f32x4 h4 = *(const f32x4*)(hp + cc * 4);
          #pragma unroll
          for (int g = 0; g < 4; ++g) {
            acc[b4][g] = fmaf(h4[0], w[g][cc][0], acc[b4][g]);
            acc[b4][g] = fmaf(h4[1], w[g][cc][1], acc[b4][g]);
            acc[b4][g] = fmaf(h4[2], w[g][cc][2], acc[b4][g]);
            acc[b4][g] = fmaf(h4[3], w[g][cc][3], acc[b4][g]);
          }
        }
      }

      // ---- 16-way k-combine via padded LDS partials ----
      #pragma unroll
      for (int b4 = 0; b4 < 4; ++b4) {
        f32x4 p = { acc[b4][0], acc[b4][1], acc[b4][2], acc[b4][3] };
        part[((bt * 4 + b4) * 8 + ul) * 17 + kq] = p;
      }
      __syncthreads();   // (B) partials complete; hstage free for prefetch

      // ---- finish (waves 0-1): LSTM cell update, coherent h store ----
      if (tid < 128) {
        float gi = bi, gj = bj, gf = bfv, go = bo;
        #pragma unroll
        for (int q = 0; q < 16; ++q) {
          const f32x4 p = part[tid * 17 + q];
          gi += p[0]; gj += p[1]; gf += p[2]; go += p[3];
        }
        const float ig = 1.f / (1.f + expf(-gi));
        const float jt = tanhf(gj);
        const float fg = 1.f / (1.f + expf(-(gf + 1.0f)));
        const float og = 1.f / (1.f + expf(-go));
        cst = fg * cst + ig * jt;
        const float hn = og * tanhf(cst);

        float* hb = taskB
            ? (h2buf + (size_t)(s & 1) * HBUF_FLOATS)         // h2(s-2)
            : (h1buf + (size_t)(s & 3) * HBUF_FLOATS);        // h1(s)
        coh_store(hb + (size_t)(bgrp * 16 + (tid >> 3)) * HH + ublk * 8 + (tid & 7), hn);
        asm volatile("s_waitcnt vmcnt(0)" ::: "memory");       // h before flag
      }
    }

    // ---- finisher-direct flag store (dense; also when inactive) ----
    if (s <= TT && tid < 128 && (tid & 63) == 0)
      coh_store_i(myflag + (tid >> 6), s + 1);

    // ---- prefetch NEXT body's low half into LDS (even waves, BLOCKING) ----
    // Hides in the barrier wait below; no in-flight regs cross opaque code.
    if (evenW) {
      if (!taskB) {
        if (s + 1 < TT) {   // x(s+1)
          const float* bx = x + ((size_t)(bgrp * 16 + rS) * TT + (s + 1)) * HH + lane * 4;
          f32x4 v0 = *(const f32x4*)(bx);
          f32x4 v1 = *(const f32x4*)(bx + rstep);
          f32x4 v2 = *(const f32x4*)(bx + 2 * rstep);
          f32x4 v3 = *(const f32x4*)(bx + 3 * rstep);
          *(f32x4*)&hstage[(rS + 0)  * HROW + dposS] = v0;
          *(f32x4*)&hstage[(rS + 4)  * HROW + dposS] = v1;
          *(f32x4*)&hstage[(rS + 8)  * HROW + dposS] = v2;
          *(f32x4*)&hstage[(rS + 12) * HROW + dposS] = v3;
        }
      } else {
        if (s >= 1 && s <= TT) {  // h1(s-1), barrier(s-1)-confirmed
          const float* p0 = h1buf + (size_t)((s - 1) & 3) * HBUF_FLOATS
                          + (size_t)(bgrp * 16 + rS) * HH + lane * 4;
          f32x4 v0, v1, v2, v3;
          coh_load4(p0, p0 + 4 * HH, p0 + 8 * HH, p0 + 12 * HH, v0, v1, v2, v3);
          *(f32x4*)&hstage[(rS + 0)  * HROW + dposS] = v0;
          *(f32x4*)&hstage[(rS + 4)  * HROW + dposS] = v1;
          *(f32x4*)&hstage[(rS + 8)  * HROW + dposS] = v2;
          *(f32x4*)&hstage[(rS + 12) * HROW + dposS] = v3;
        }
      }
    }

    // ---- lockstep barrier: wave 0 polls 64 blocks' dense flag pairs ----
    if (s <= TT) {
      if (tid < 64) {
        const int* fp = flags + ((size_t)bgrp * 64 + tid) * 2;
        for (;;) {
          i32x2 f;
          asm volatile(
              "global_load_dwordx2 %0, %1, off sc0 sc1\n\t"
              "s_waitcnt vmcnt(0)"
              : "=v"(f) : "v"(fp) : "memory");
          const int v = f[0] < f[1] ? f[0] : f[1];
          if (__all(v >= s + 1)) break;
          __builtin_amdgcn_s_sleep(1);
        }
      }
      __syncthreads();   // (C) barrier done; prefetched low half visible
    }
  }
}

// Head: logits = h2_last @ w_out + b_out; sigmoid; threshold.
__global__ void head_kernel(const float* __restrict__ h2last,
                            const float* __restrict__ w_out,
                            const float* __restrict__ b_out,
                            float* __restrict__ out)
{
  int tid = threadIdx.x;
  if (tid >= 384) return;
  int bb = tid / 6, cc = tid % 6;
  float acc = b_out[cc];
  const float* hr = h2last + bb * HH;
  #pragma unroll 4
  for (int uu = 0; uu < HH; ++uu) acc = fmaf(hr[uu], w_out[uu * 6 + cc], acc);
  out[tid] = acc;                            // logits
  float sg = 1.f / (1.f + expf(-acc));
  out[384 + tid] = sg;                       // sigmoid output
  out[768 + tid] = (sg > 0.5f) ? 1.f : 0.f;  // prediction
}

extern "C" void kernel_launch(void* const* d_in, const int* in_sizes, int n_in,
                              void* d_out, int out_size, void* d_ws, size_t ws_size,
                              hipStream_t stream) {
  const float* x     = (const float*)d_in[0];
  const float* k0    = (const float*)d_in[1];
  const float* b0    = (const float*)d_in[2];
  const float* k1    = (const float*)d_in[3];
  const float* b1    = (const float*)d_in[4];
  const float* w_out = (const float*)d_in[5];
  const float* b_out = (const float*)d_in[6];
  float* out = (float*)d_out;

  if (ws_size < WS_NEEDED) return;  // visible failure if ws too small

  int*   flags = (int*)d_ws;
  float* h1b   = (float*)((char*)d_ws + FLAG_BYTES);   // 4 slots (quad)
  float* h2b   = h1b + 4 * HBUF_FLOATS;                // 2 slots (double)
  float* wt0   = h2b + 2 * HBUF_FLOATS;
  float* wt1   = wt0 + WT_FLOATS;

  // Zero flags + all h slots (h(-1)=c(-1)=0): graph-replay deterministic.
  hipMemsetAsync(d_ws, 0, FLAG_BYTES + (size_t)6 * HBUF_FLOATS * 4, stream);

  transpose_w<<<dim3(4, 8, 4), 256, 0, stream>>>(k0, wt0);
  transpose_w<<<dim3(4, 8, 4), 256, 0, stream>>>(k1, wt1);

  lstm2_persistent<<<256, NTHREADS, 0, stream>>>(x, b0, b1, wt0, wt1,
                                                 h1b, h2b, flags);

  // h2(1023) lives in slot 1023&1 = 1
  head_kernel<<<1, 384, 0, stream>>>(h2b + HBUF_FLOATS, w_out, b_out, out);
}